// Round 1
// baseline (1261.352 us; speedup 1.0000x reference)
//
#include <hip/hip_runtime.h>

typedef __attribute__((ext_vector_type(8))) short bf16x8;
typedef __attribute__((ext_vector_type(4))) float f32x4;
typedef __attribute__((ext_vector_type(4))) int   i32x4;

#define DEV static __device__ __forceinline__

constexpr int BATCH = 512;
constexpr int TENC  = 64;
constexpr int DIN   = 512;
constexpr int HDIM  = 512;
constexpr int NCLS  = 38;
constexpr int STEPS = 26;
constexpr int NG    = 4 * HDIM;   // 2048

// ---- workspace layout (bytes) ----
constexpr size_t HP_OFF   = 0;                                   // bf16 [B*T][512]  H_proj
constexpr size_t HP_SZ    = (size_t)BATCH * TENC * HDIM * 2;
constexpr size_t ENC_OFF  = HP_OFF + HP_SZ;                      // bf16 [B*T][512]  encoder
constexpr size_t ENC_SZ   = (size_t)BATCH * TENC * DIN * 2;
constexpr size_t A2_OFF   = ENC_OFF + ENC_SZ;                    // bf16 [B][1024]   [ctx | h]
constexpr size_t A2_SZ    = (size_t)BATCH * 1024 * 2;
constexpr size_t C32_OFF  = A2_OFF + A2_SZ;                      // f32 [B][512]     cell state
constexpr size_t C32_SZ   = (size_t)BATCH * HDIM * 4;
constexpr size_t HP32_OFF = C32_OFF + C32_SZ;                    // f32 [B][512]     h@w_h2h.T + b
constexpr size_t HP32_SZ  = (size_t)BATCH * HDIM * 4;
constexpr size_t B2R_OFF  = HP32_OFF + HP32_SZ;                  // bf16 [2048][1024] [w_ih_d | w_hh], gate-interleaved
constexpr size_t B2R_SZ   = (size_t)NG * 1024 * 2;
constexpr size_t WI2H_OFF = B2R_OFF + B2R_SZ;                    // bf16 [512][512]
constexpr size_t WI2H_SZ  = (size_t)HDIM * DIN * 2;
constexpr size_t B3_OFF   = WI2H_OFF + WI2H_SZ;                  // bf16 [576][512]  [w_h2h ; w_gen ; pad]
constexpr size_t B3_SZ    = (size_t)576 * HDIM * 2;
constexpr size_t WOH_OFF  = B3_OFF + B3_SZ;                      // f32 [2048][38]   one-hot columns, interleaved
constexpr size_t WOH_SZ   = (size_t)NG * NCLS * 4;
constexpr size_t BIAS_OFF = WOH_OFF + WOH_SZ;                    // f32 [2048]       b_ih+b_hh interleaved
constexpr size_t BIAS_SZ  = (size_t)NG * 4;

DEV float bf2f(unsigned short s) {
    unsigned u = ((unsigned)s) << 16;
    return __builtin_bit_cast(float, u);
}
DEV unsigned short f2bf(float f) {
    unsigned u = __builtin_bit_cast(unsigned, f);
    u = (u + 0x7fffu + ((u >> 16) & 1u)) >> 16;   // RNE
    return (unsigned short)u;
}
DEV float sigmoid_f(float x) { return 1.f / (1.f + __expf(-x)); }
DEV float tanh_f(float x) {
    x = fminf(fmaxf(x, -15.f), 15.f);
    float e = __expf(2.f * x);
    return (e - 1.f) / (e + 1.f);
}

// ---------------- conversion / init kernels ----------------
__global__ void conv_bf16_kernel(const float* __restrict__ in,
                                 unsigned short* __restrict__ out, int n4) {
    int i = blockIdx.x * blockDim.x + threadIdx.x;
    int stride = gridDim.x * blockDim.x;
    for (; i < n4; i += stride) {
        float4 v = ((const float4*)in)[i];
        ushort4 o;
        o.x = f2bf(v.x); o.y = f2bf(v.y); o.z = f2bf(v.z); o.w = f2bf(v.w);
        ((ushort4*)out)[i] = o;
    }
}

// Build gate-interleaved [w_ih(:,:512) | w_hh] (n' = u*4+g <- row g*512+u), plus
// interleaved one-hot columns (fp32) and combined bias.
__global__ void build_b2r_kernel(const float* __restrict__ w_ih, const float* __restrict__ w_hh,
                                 const float* __restrict__ b_ih, const float* __restrict__ b_hh,
                                 unsigned short* __restrict__ B2r, float* __restrict__ woh,
                                 float* __restrict__ bias2r) {
    int np = blockIdx.x;            // 0..2047
    int u = np >> 2, g = np & 3;
    int src = g * 512 + u;
    for (int k = threadIdx.x; k < 512; k += blockDim.x) {
        B2r[np * 1024 + k]       = f2bf(w_ih[src * 550 + k]);
        B2r[np * 1024 + 512 + k] = f2bf(w_hh[src * 512 + k]);
    }
    if (threadIdx.x < NCLS) woh[np * NCLS + threadIdx.x] = w_ih[src * 550 + 512 + threadIdx.x];
    if (threadIdx.x == 0)   bias2r[np] = b_ih[src] + b_hh[src];
}

__global__ void build_b3_kernel(const float* __restrict__ w_h2h, const float* __restrict__ w_gen,
                                unsigned short* __restrict__ B3) {
    int n = blockIdx.x;             // 0..575
    for (int k = threadIdx.x; k < 512; k += blockDim.x) {
        float v = 0.f;
        if (n < 512)      v = w_h2h[n * 512 + k];
        else if (n < 550) v = w_gen[(n - 512) * 512 + k];
        B3[n * 512 + k] = f2bf(v);
    }
}

__global__ void init_state_kernel(float* __restrict__ c32, float* __restrict__ hp32,
                                  unsigned short* __restrict__ A2,
                                  const float* __restrict__ b_h2h) {
    int b = blockIdx.x;
    for (int j = threadIdx.x; j < 512; j += blockDim.x) {
        c32[b * 512 + j]  = 0.f;
        hp32[b * 512 + j] = b_h2h[j];          // h0 = 0 -> hp = b_h2h
        A2[b * 1024 + 512 + j] = 0;            // h part of A2 = 0 (bf16 zero)
    }
}

// ---------------- MFMA GEMM core: C[m0:BM, n0:BN] += A[M,K] * B[N,K]^T ----------------
// A, B row-major bf16; 4 waves in 2x2; wave tile = (FRM*16) x (FRN*16).
template<int BM, int BN, int FRM, int FRN>
DEV void gemm_core(const unsigned short* __restrict__ A, int ldA,
                   const unsigned short* __restrict__ Bm, int ldB, int K,
                   int m0, int n0, unsigned short* lA, unsigned short* lB,
                   f32x4 acc[FRM][FRN]) {
    constexpr int LSTR = 56;  // bf16 elems per LDS row: 112B, 16B-aligned, ~2-way banks
    const int tid  = threadIdx.x;
    const int lane = tid & 63;
    const int wid  = tid >> 6;
    const int wm = wid >> 1, wn = wid & 1;
    const int fr_row = lane & 15;
    const int fr_kb  = (lane >> 4) * 8;

    for (int k0 = 0; k0 < K; k0 += 32) {
        #pragma unroll
        for (int uu = 0; uu < BM * 4; uu += 256) {
            int u = uu + tid;
            int r = u >> 2, cb = u & 3;
            i32x4 v = *(const i32x4*)(A + (size_t)(m0 + r) * ldA + k0 + cb * 8);
            *(i32x4*)(lA + r * LSTR + cb * 8) = v;
        }
        #pragma unroll
        for (int uu = 0; uu < BN * 4; uu += 256) {
            int u = uu + tid;
            int r = u >> 2, cb = u & 3;
            i32x4 v = *(const i32x4*)(Bm + (size_t)(n0 + r) * ldB + k0 + cb * 8);
            *(i32x4*)(lB + r * LSTR + cb * 8) = v;
        }
        __syncthreads();
        bf16x8 af[FRM], bfv[FRN];
        #pragma unroll
        for (int i = 0; i < FRM; i++)
            af[i] = *(const bf16x8*)(lA + (wm * FRM * 16 + i * 16 + fr_row) * LSTR + fr_kb);
        #pragma unroll
        for (int j = 0; j < FRN; j++)
            bfv[j] = *(const bf16x8*)(lB + (wn * FRN * 16 + j * 16 + fr_row) * LSTR + fr_kb);
        #pragma unroll
        for (int i = 0; i < FRM; i++)
            #pragma unroll
            for (int j = 0; j < FRN; j++)
                acc[i][j] = __builtin_amdgcn_mfma_f32_16x16x32_bf16(af[i], bfv[j], acc[i][j], 0, 0, 0);
        __syncthreads();
    }
}

// ---------------- H_proj GEMM (bf16 output) ----------------
template<int BM, int BN, int FRM, int FRN>
__global__ __launch_bounds__(256) void gemm_bf16out_kernel(
    const unsigned short* __restrict__ A, int ldA,
    const unsigned short* __restrict__ Bm, int ldB,
    unsigned short* __restrict__ C, int ldC, int K) {
    __shared__ unsigned short lA[BM * 56], lB[BN * 56];
    int m0 = blockIdx.x * BM, n0 = blockIdx.y * BN;
    f32x4 acc[FRM][FRN] = {};
    gemm_core<BM, BN, FRM, FRN>(A, ldA, Bm, ldB, K, m0, n0, lA, lB, acc);
    const int lane = threadIdx.x & 63, wid = threadIdx.x >> 6;
    const int wm = wid >> 1, wn = wid & 1;
    #pragma unroll
    for (int i = 0; i < FRM; i++)
        #pragma unroll
        for (int j = 0; j < FRN; j++)
            #pragma unroll
            for (int r = 0; r < 4; r++) {
                int m = m0 + wm * FRM * 16 + i * 16 + (lane >> 4) * 4 + r;
                int n = n0 + wn * FRN * 16 + j * 16 + (lane & 15);
                C[(size_t)m * ldC + n] = f2bf(acc[i][j][r]);
            }
}

// ---------------- gates GEMM + fused LSTM pointwise ----------------
__global__ __launch_bounds__(256) void gates_kernel(
    const unsigned short* __restrict__ A2,   // [512][1024] bf16 [ctx|h]
    const unsigned short* __restrict__ B2r,  // [2048][1024] bf16, gate-interleaved
    const float* __restrict__ bias2r, const float* __restrict__ woh,
    const int* __restrict__ text, int step,
    float* __restrict__ c32, unsigned short* __restrict__ A2h /* = A2 + 512 */) {
    constexpr int BM = 64, BN = 64, FRM = 2, FRN = 2;
    __shared__ unsigned short lA[BM * 56], lB[BN * 56];
    __shared__ float gbuf[64][64];
    int m0 = blockIdx.x * BM, n0 = blockIdx.y * BN;
    f32x4 acc[FRM][FRN] = {};
    gemm_core<BM, BN, FRM, FRN>(A2, 1024, B2r, 1024, 1024, m0, n0, lA, lB, acc);
    const int lane = threadIdx.x & 63, wid = threadIdx.x >> 6;
    const int wm = wid >> 1, wn = wid & 1;
    #pragma unroll
    for (int i = 0; i < FRM; i++)
        #pragma unroll
        for (int j = 0; j < FRN; j++)
            #pragma unroll
            for (int r = 0; r < 4; r++) {
                int ml = wm * 32 + i * 16 + (lane >> 4) * 4 + r;
                int nl = wn * 32 + j * 16 + (lane & 15);
                gbuf[ml][nl] = acc[i][j][r];
            }
    __syncthreads();
    // pointwise LSTM: each block tile covers 64 rows x 16 complete units
    for (int idx = threadIdx.x; idx < 64 * 16; idx += 256) {
        int rl = idx >> 4, uu = idx & 15;
        int b  = m0 + rl;
        int nb = n0 + uu * 4;        // global n' of the i-gate
        int u  = nb >> 2;            // global unit index
        int tb = text[b * STEPS + step];
        float4 g4 = *(const float4*)&gbuf[rl][uu * 4];
        float vi = g4.x + bias2r[nb + 0] + woh[(nb + 0) * NCLS + tb];
        float vf = g4.y + bias2r[nb + 1] + woh[(nb + 1) * NCLS + tb];
        float vg = g4.z + bias2r[nb + 2] + woh[(nb + 2) * NCLS + tb];
        float vo = g4.w + bias2r[nb + 3] + woh[(nb + 3) * NCLS + tb];
        float c_old = c32[b * 512 + u];
        float cn = sigmoid_f(vf) * c_old + sigmoid_f(vi) * tanh_f(vg);
        float hn = sigmoid_f(vo) * tanh_f(cn);
        c32[b * 512 + u] = cn;
        A2h[b * 1024 + u] = f2bf(hn);
    }
}

// ---------------- h @ [w_h2h ; w_gen]^T : next-step hp + probs output ----------------
__global__ __launch_bounds__(256) void hp_probs_kernel(
    const unsigned short* __restrict__ Ah,   // A2 + 512 (h part), ld 1024
    const unsigned short* __restrict__ B3,   // [576][512] bf16
    float* __restrict__ hp32, float* __restrict__ out,
    const float* __restrict__ b_h2h, const float* __restrict__ b_gen, int step) {
    constexpr int BM = 64, BN = 64, FRM = 2, FRN = 2;
    __shared__ unsigned short lA[BM * 56], lB[BN * 56];
    int m0 = blockIdx.x * BM, n0 = blockIdx.y * BN;
    f32x4 acc[FRM][FRN] = {};
    gemm_core<BM, BN, FRM, FRN>(Ah, 1024, B3, 512, 512, m0, n0, lA, lB, acc);
    const int lane = threadIdx.x & 63, wid = threadIdx.x >> 6;
    const int wm = wid >> 1, wn = wid & 1;
    #pragma unroll
    for (int i = 0; i < FRM; i++)
        #pragma unroll
        for (int j = 0; j < FRN; j++)
            #pragma unroll
            for (int r = 0; r < 4; r++) {
                int m = m0 + wm * 32 + i * 16 + (lane >> 4) * 4 + r;
                int n = n0 + wn * 32 + j * 16 + (lane & 15);
                float v = acc[i][j][r];
                if (n < 512)      hp32[m * 512 + n] = v + b_h2h[n];
                else if (n < 550) out[((size_t)m * STEPS + step) * NCLS + (n - 512)] = v + b_gen[n - 512];
            }
}

// ---------------- attention step: e -> softmax -> context (per batch row) ----------------
__global__ __launch_bounds__(256) void attn_kernel(
    const unsigned short* __restrict__ Hp,   // [B*T][512] bf16
    const unsigned short* __restrict__ enc,  // [B*T][512] bf16
    const float* __restrict__ hp32,          // [B][512]
    const float* __restrict__ w_score,       // [512]
    unsigned short* __restrict__ A2) {       // ctx -> A2[b][0:512] bf16
    int b = blockIdx.x;
    int tid = threadIdx.x;
    int lane = tid & 63, wid = tid >> 6;
    __shared__ float e_lds[64];
    __shared__ float alpha_lds[64];

    float hp8[8], ws8[8];
    {
        const float4* hp4 = (const float4*)(hp32 + b * 512 + lane * 8);
        const float4* ws4 = (const float4*)(w_score + lane * 8);
        float4 h0 = hp4[0], h1 = hp4[1];
        float4 w0 = ws4[0], w1 = ws4[1];
        hp8[0] = h0.x; hp8[1] = h0.y; hp8[2] = h0.z; hp8[3] = h0.w;
        hp8[4] = h1.x; hp8[5] = h1.y; hp8[6] = h1.z; hp8[7] = h1.w;
        ws8[0] = w0.x; ws8[1] = w0.y; ws8[2] = w0.z; ws8[3] = w0.w;
        ws8[4] = w1.x; ws8[5] = w1.y; ws8[6] = w1.z; ws8[7] = w1.w;
    }
    // e[t] = sum_h w_score[h] * tanh(Hp[b,t,h] + hp[b,h]); 4 waves, 16 t's each
    for (int t = wid; t < 64; t += 4) {
        bf16x8 hv = *(const bf16x8*)(Hp + ((size_t)b * 64 + t) * 512 + lane * 8);
        float acc = 0.f;
        #pragma unroll
        for (int j = 0; j < 8; j++)
            acc += ws8[j] * tanh_f(hp8[j] + bf2f((unsigned short)hv[j]));
        #pragma unroll
        for (int off = 32; off > 0; off >>= 1) acc += __shfl_down(acc, off);
        if (lane == 0) e_lds[t] = acc;
    }
    __syncthreads();
    if (wid == 0) {   // softmax over 64 t in one wave
        float v = e_lds[lane];
        float m = v;
        #pragma unroll
        for (int off = 32; off > 0; off >>= 1) m = fmaxf(m, __shfl_xor(m, off));
        float ex = __expf(v - m);
        float s = ex;
        #pragma unroll
        for (int off = 32; off > 0; off >>= 1) s += __shfl_xor(s, off);
        alpha_lds[lane] = ex / s;
    }
    __syncthreads();
    // context: thread handles cols (2*tid, 2*tid+1); coalesced 2xbf16 per t
    float a0 = 0.f, a1 = 0.f;
    const unsigned short* erow = enc + (size_t)b * 64 * 512 + tid * 2;
    for (int t = 0; t < 64; t++) {
        float al = alpha_lds[t];
        unsigned pv = *(const unsigned*)(erow + (size_t)t * 512);
        a0 += al * bf2f((unsigned short)(pv & 0xffffu));
        a1 += al * bf2f((unsigned short)(pv >> 16));
    }
    unsigned short o0 = f2bf(a0), o1 = f2bf(a1);
    *(unsigned*)(A2 + (size_t)b * 1024 + tid * 2) = ((unsigned)o1 << 16) | (unsigned)o0;
}

// ---------------- host ----------------
extern "C" void kernel_launch(void* const* d_in, const int* in_sizes, int n_in,
                              void* d_out, int out_size, void* d_ws, size_t ws_size,
                              hipStream_t stream) {
    (void)in_sizes; (void)n_in; (void)out_size; (void)ws_size;
    const float* enc_f   = (const float*)d_in[0];
    const int*   text    = (const int*)d_in[1];
    const float* w_i2h   = (const float*)d_in[2];
    const float* w_h2h   = (const float*)d_in[3];
    const float* b_h2h   = (const float*)d_in[4];
    const float* w_score = (const float*)d_in[5];
    const float* w_ih    = (const float*)d_in[6];
    const float* w_hh    = (const float*)d_in[7];
    const float* b_ih    = (const float*)d_in[8];
    const float* b_hh    = (const float*)d_in[9];
    const float* w_gen   = (const float*)d_in[10];
    const float* b_gen   = (const float*)d_in[11];
    float* out = (float*)d_out;

    char* ws = (char*)d_ws;
    unsigned short* Hp     = (unsigned short*)(ws + HP_OFF);
    unsigned short* encb   = (unsigned short*)(ws + ENC_OFF);
    unsigned short* A2     = (unsigned short*)(ws + A2_OFF);
    float*          c32    = (float*)(ws + C32_OFF);
    float*          hp32   = (float*)(ws + HP32_OFF);
    unsigned short* B2r    = (unsigned short*)(ws + B2R_OFF);
    unsigned short* wi2hb  = (unsigned short*)(ws + WI2H_OFF);
    unsigned short* B3     = (unsigned short*)(ws + B3_OFF);
    float*          woh    = (float*)(ws + WOH_OFF);
    float*          bias2r = (float*)(ws + BIAS_OFF);

    conv_bf16_kernel<<<2048, 256, 0, stream>>>(enc_f, encb, BATCH * TENC * DIN / 4);
    conv_bf16_kernel<<<256, 256, 0, stream>>>(w_i2h, wi2hb, HDIM * DIN / 4);
    build_b2r_kernel<<<NG, 256, 0, stream>>>(w_ih, w_hh, b_ih, b_hh, B2r, woh, bias2r);
    build_b3_kernel<<<576, 256, 0, stream>>>(w_h2h, w_gen, B3);
    init_state_kernel<<<BATCH, 256, 0, stream>>>(c32, hp32, A2, b_h2h);

    // H_proj = enc @ w_i2h^T  (M=32768, N=512, K=512)
    gemm_bf16out_kernel<128, 128, 4, 4><<<dim3(BATCH * TENC / 128, HDIM / 128), 256, 0, stream>>>(
        encb, DIN, wi2hb, DIN, Hp, HDIM, DIN);

    for (int s = 0; s < STEPS; s++) {
        attn_kernel<<<BATCH, 256, 0, stream>>>(Hp, encb, hp32, w_score, A2);
        gates_kernel<<<dim3(BATCH / 64, NG / 64), 256, 0, stream>>>(
            A2, B2r, bias2r, woh, text, s, c32, A2 + 512);
        hp_probs_kernel<<<dim3(BATCH / 64, 576 / 64), 256, 0, stream>>>(
            A2 + 512, B3, hp32, out, b_h2h, b_gen, s);
    }
}